// Round 5
// baseline (11539.053 us; speedup 1.0000x reference)
//
#include <hip/hip_runtime.h>
#include <stdint.h>

typedef unsigned short u16;
typedef __bf16 bf16x8 __attribute__((ext_vector_type(8)));
typedef float f32x4 __attribute__((ext_vector_type(4)));

#define B_   1024
#define N_   31
#define D_   576
#define H_   16
#define L_   12
#define DH_  36
#define FF_  2304
#define NC_  1000
#define M_   (B_*N_)          // 31744 tokens
#define NCHUNK 4
#define BC_  (B_/NCHUNK)      // 256 batches per chunk
#define MC_  (BC_*N_)         // 7936 rows per chunk (= 31 x 256-row tiles)
#define NEG_ (-987654321.0f)

// ---------- helpers ----------
__device__ __forceinline__ u16 f2bfbits(float f) {
  uint32_t x = __builtin_bit_cast(uint32_t, f);
  x += 0x7fffu + ((x >> 16) & 1u);   // RNE
  return (u16)(x >> 16);
}
__device__ __forceinline__ float bfbits2f(u16 u) {
  return __builtin_bit_cast(float, (uint32_t)u << 16);
}
__device__ __forceinline__ float lo_bf(uint32_t w) {
  return __builtin_bit_cast(float, w << 16);
}
__device__ __forceinline__ float hi_bf(uint32_t w) {
  return __builtin_bit_cast(float, w & 0xffff0000u);
}

typedef __attribute__((address_space(1))) void gvoid_t;
typedef __attribute__((address_space(3))) void lvoid_t;
__device__ __forceinline__ void async16(void* lds, const void* g) {
  __builtin_amdgcn_global_load_lds((gvoid_t*)const_cast<void*>(g), (lvoid_t*)lds, 16, 0, 0);
}

// ---------- GEMM: C[M,N] = A[M,K](bf16) * Bw[N,K](bf16)^T  + epilogue ----------
// BM=256, BN=64, BK=32. 256 threads = 4 waves, wave w owns rows [w*64, w*64+64) x 64 cols.
// EPI: 0 = store bf16 (QKV)
//      1 = resid[r*N+c] += acc + bias[c]   (f32 in-place; outproj / FC2)
//      2 = store bf16 gelu(acc + bias[c])  (FC1)
//      3 = outf[r*Nreal+c] = acc + bias[c] if c < Nreal  (head, f32)
template<int EPI>
__global__ __launch_bounds__(256, 2)
void gemm_bt(const u16* __restrict__ A, const u16* __restrict__ Bw,
             int N, int K,
             const float* __restrict__ bias,
             float* __restrict__ resid,
             u16* __restrict__ outb,
             float* __restrict__ outf, int Nreal)
{
  __shared__ alignas(16) u16 As[256 * 32];   // 16 KB
  __shared__ alignas(16) u16 Bs[64 * 32];    // 4 KB

  const int t    = threadIdx.x;
  const int wave = t >> 6;
  const int lane = t & 63;
  const int mBase = blockIdx.y * 256;
  const int nBase = blockIdx.x * 64;

  const int tr = t >> 2;          // 0..63 staging row within issue
  const int tc = (t & 3) * 8;     // staging col (elements)

  const int fr = lane & 15;
  const int fk = (lane >> 4) * 8;
  const u16* aBase = &As[(wave * 64 + fr) * 32 + fk];
  const u16* bBase = &Bs[fr * 32 + fk];

  f32x4 acc[4][4] = {};

  for (int k0 = 0; k0 < K; k0 += 32) {
    // stage A tile (256x32) : 4 issues, and B tile (64x32) : 1 issue
    #pragma unroll
    for (int i = 0; i < 4; ++i) {
      int row = i * 64 + tr;
      async16(&As[row * 32 + tc], A + (long)(mBase + row) * K + k0 + tc);
    }
    async16(&Bs[tr * 32 + tc], Bw + (long)(nBase + tr) * K + k0 + tc);
    asm volatile("s_waitcnt vmcnt(0)" ::: "memory");
    __syncthreads();

    bf16x8 af[4], bf_[4];
    #pragma unroll
    for (int m = 0; m < 4; ++m) af[m]  = *(const bf16x8*)(aBase + m * 16 * 32);
    #pragma unroll
    for (int n = 0; n < 4; ++n) bf_[n] = *(const bf16x8*)(bBase + n * 16 * 32);
    #pragma unroll
    for (int m = 0; m < 4; ++m)
      #pragma unroll
      for (int n = 0; n < 4; ++n)
        acc[m][n] = __builtin_amdgcn_mfma_f32_16x16x32_bf16(af[m], bf_[n], acc[m][n], 0, 0, 0);
    __syncthreads();
  }

  // epilogue: D layout col = lane&15, row = (lane>>4)*4 + reg  [m89-verified]
  const int fq = lane >> 4;
  #pragma unroll
  for (int m = 0; m < 4; ++m) {
    int gr0 = mBase + wave * 64 + m * 16 + fq * 4;
    #pragma unroll
    for (int n = 0; n < 4; ++n) {
      int gc = nBase + n * 16 + fr;
      #pragma unroll
      for (int r = 0; r < 4; ++r) {
        long gr = gr0 + r;
        float v = acc[m][n][r];
        if (EPI == 0) {
          outb[gr * N + gc] = f2bfbits(v);
        } else if (EPI == 1) {
          long idx = gr * N + gc;
          resid[idx] = resid[idx] + v + bias[gc];
        } else if (EPI == 2) {
          float x = v + bias[gc];
          float g = 0.5f * x * (1.0f + erff(x * 0.70710678118654752f));
          outb[gr * N + gc] = f2bfbits(g);
        } else {
          if (gc < Nreal) outf[gr * Nreal + gc] = v + bias[gc];
        }
      }
    }
  }
}

// ---------- LayerNorm: one wave per token (D=576 = 64 lanes * 9) ----------
__global__ __launch_bounds__(256)
void ln_kernel(const float* __restrict__ x, long tokStride,
               const float* __restrict__ w, const float* __restrict__ b,
               u16* __restrict__ y)
{
  int tok  = blockIdx.x * 4 + (threadIdx.x >> 6);
  int lane = threadIdx.x & 63;
  const float* row = x + (long)tok * tokStride;
  float v[9]; float s = 0.f, sq = 0.f;
  #pragma unroll
  for (int j = 0; j < 9; ++j) { v[j] = row[lane + j * 64]; s += v[j]; sq += v[j] * v[j]; }
  #pragma unroll
  for (int o = 32; o; o >>= 1) { s += __shfl_xor(s, o); sq += __shfl_xor(sq, o); }
  float mean = s * (1.f / 576.f);
  float var  = sq * (1.f / 576.f) - mean * mean;
  float inv  = rsqrtf(var + 1e-5f);
  u16* yr = y + (long)tok * 576;
  #pragma unroll
  for (int j = 0; j < 9; ++j) {
    int c = lane + j * 64;
    yr[c] = f2bfbits((v[j] - mean) * inv * w[c] + b[c]);
  }
}

// ---------- Attention: one wave per (local b, h). N=31, DH=36. diag masked. ----------
// qkv: [BC_*31, 1728] chunk, o: [BC_*31, 576] chunk
__global__ __launch_bounds__(256)
void attn_kernel(const u16* __restrict__ qkv, u16* __restrict__ o,
                 const float* __restrict__ scale)
{
  __shared__ float kls[4][N_ * DH_];
  __shared__ float vls[4][N_ * DH_];
  int wave = threadIdx.x >> 6, lane = threadIdx.x & 63;
  int bh = blockIdx.x * 4 + wave;
  int b  = bh >> 4, h = bh & 15;
  long base = (long)b * N_ * 1728 + h * DH_;

  // stage K,V rows (31 x 36 bf16 each) as f32 into LDS; 558 dword loads each
  for (int u = lane; u < 558; u += 64) {
    int row = u / 18, c = (u % 18) * 2;
    uint32_t kw = *(const uint32_t*)(qkv + base + 576  + (long)row * 1728 + c);
    uint32_t vw = *(const uint32_t*)(qkv + base + 1152 + (long)row * 1728 + c);
    kls[wave][row * 36 + c]     = lo_bf(kw);
    kls[wave][row * 36 + c + 1] = hi_bf(kw);
    vls[wave][row * 36 + c]     = lo_bf(vw);
    vls[wave][row * 36 + c + 1] = hi_bf(vw);
  }
  __syncthreads();

  // 2 lanes per query row: lane = 2*i + p, p splits d into halves of 18
  int i0 = lane >> 1, p = lane & 1;
  int i  = i0 > 30 ? 30 : i0;
  float qv[18];
  const u16* qrow = qkv + base + (long)i * 1728 + p * 18;
  #pragma unroll
  for (int d = 0; d < 18; ++d) qv[d] = bfbits2f(qrow[d]);

  float s[31];
  #pragma unroll
  for (int j = 0; j < 31; ++j) {
    float a = 0.f;
    const float* kr = &kls[wave][j * 36 + p * 18];
    #pragma unroll
    for (int d = 0; d < 18; ++d) a += qv[d] * kr[d];
    a += __shfl_xor(a, 1);           // combine the two d-halves
    s[j] = a;
  }
  float sc = scale[h];
  float mx = -1e30f;
  #pragma unroll
  for (int j = 0; j < 31; ++j) { s[j] = (j == i) ? NEG_ : s[j] * sc; mx = fmaxf(mx, s[j]); }
  float sum = 0.f;
  #pragma unroll
  for (int j = 0; j < 31; ++j) { s[j] = expf(s[j] - mx); sum += s[j]; }
  float inv = 1.f / sum;

  #pragma unroll
  for (int d = 0; d < 18; ++d) {
    float a = 0.f;
    #pragma unroll
    for (int j = 0; j < 31; ++j) a += s[j] * vls[wave][j * 36 + p * 18 + d];
    if (i0 < 31)
      o[(long)(b * N_ + i0) * 576 + h * DH_ + p * 18 + d] = f2bfbits(a * inv);
  }
}

// ---------- f32 -> bf16 weight conversion ----------
__global__ void cvt4(const float4* __restrict__ in, u16* __restrict__ out, int n4)
{
  int idx = blockIdx.x * 256 + threadIdx.x;
  if (idx >= n4) return;
  float4 v = in[idx];
  ushort4 r;
  r.x = f2bfbits(v.x); r.y = f2bfbits(v.y); r.z = f2bfbits(v.z); r.w = f2bfbits(v.w);
  *(ushort4*)(out + (long)idx * 4) = r;
}

// head_w (1000x576) -> bf16 padded to 1024 rows (zeros)
__global__ void pad_head(const float* __restrict__ hw, u16* __restrict__ out)
{
  int idx = blockIdx.x * 256 + threadIdx.x;   // < 1024*576
  int row = idx / 576;
  out[idx] = (row < NC_) ? f2bfbits(hw[idx]) : (u16)0;
}

// ---------- launch ----------
extern "C" void kernel_launch(void* const* d_in, const int* in_sizes, int n_in,
                              void* d_out, int out_size, void* d_ws, size_t ws_size,
                              hipStream_t stream)
{
  (void)in_sizes; (void)n_in; (void)out_size; (void)ws_size;
  const float* x      = (const float*)d_in[0];
  const float* qkv_w  = (const float*)d_in[1];
  const float* scale  = (const float*)d_in[2];
  const float* out_w  = (const float*)d_in[3];
  const float* out_b  = (const float*)d_in[4];
  const float* ln1_w  = (const float*)d_in[5];
  const float* ln1_b  = (const float*)d_in[6];
  const float* ln2_w  = (const float*)d_in[7];
  const float* ln2_b  = (const float*)d_in[8];
  const float* fc1_w  = (const float*)d_in[9];
  const float* fc1_b  = (const float*)d_in[10];
  const float* fc2_w  = (const float*)d_in[11];
  const float* fc2_b  = (const float*)d_in[12];
  const float* norm_w = (const float*)d_in[13];
  const float* norm_b = (const float*)d_in[14];
  const float* head_w = (const float*)d_in[15];
  const float* head_b = (const float*)d_in[16];

  // ---- workspace layout (~154 MB total; chunked to stay well under ws_size) ----
  char* p = (char*)d_ws;
  auto take = [&](size_t bytes) { char* r = p; p += (bytes + 255) & ~(size_t)255; return r; };
  float* h    = (float*)take((size_t)M_ * D_ * 4);          // residual stream f32   69.8 MB
  u16*   ybuf = (u16*)take((size_t)M_ * D_ * 2);            // LN out / attn out     36.6 MB
  u16*   cbuf = (u16*)take((size_t)MC_ * FF_ * 2);          // chunk qkv / mlp mid   36.6 MB
  u16*   wq_l = (u16*)take((size_t)1728 * D_ * 2);          // per-layer bf16 weights 8 MB
  u16*   wo_l = (u16*)take((size_t)D_ * D_ * 2);
  u16*   w1_l = (u16*)take((size_t)FF_ * D_ * 2);
  u16*   w2_l = (u16*)take((size_t)D_ * FF_ * 2);
  u16*   whead = (u16*)take((size_t)1024 * D_ * 2);         // 1.2 MB
  u16*   cls   = (u16*)take((size_t)1024 * D_ * 2);         // 1.2 MB

  auto cvt = [&](const float* src, u16* dst, size_t n) {
    int n4 = (int)(n / 4);
    cvt4<<<(n4 + 255) / 256, 256, 0, stream>>>((const float4*)src, dst, n4);
  };
  pad_head<<<(1024 * 576) / 256, 256, 0, stream>>>(head_w, whead);
  hipMemcpyAsync(h, x, (size_t)M_ * D_ * 4, hipMemcpyDeviceToDevice, stream);

  for (int l = 0; l < L_; ++l) {
    cvt(qkv_w + (size_t)l * 1728 * D_, wq_l, (size_t)1728 * D_);
    cvt(out_w + (size_t)l * D_ * D_,  wo_l, (size_t)D_ * D_);
    cvt(fc1_w + (size_t)l * FF_ * D_, w1_l, (size_t)FF_ * D_);
    cvt(fc2_w + (size_t)l * D_ * FF_, w2_l, (size_t)D_ * FF_);

    ln_kernel<<<M_ / 4, 256, 0, stream>>>(h, 576, ln1_w + l * D_, ln1_b + l * D_, ybuf);
    for (int c = 0; c < NCHUNK; ++c) {
      long off = (long)c * MC_;
      gemm_bt<0><<<dim3(1728 / 64, MC_ / 256), 256, 0, stream>>>(
          ybuf + off * D_, wq_l, 1728, 576, nullptr, nullptr, cbuf, nullptr, 0);
      attn_kernel<<<(BC_ * H_) / 4, 256, 0, stream>>>(cbuf, ybuf + off * D_, scale + l * H_);
      gemm_bt<1><<<dim3(576 / 64, MC_ / 256), 256, 0, stream>>>(
          ybuf + off * D_, wo_l, 576, 576, out_b + l * D_, h + off * D_, nullptr, nullptr, 0);
    }
    ln_kernel<<<M_ / 4, 256, 0, stream>>>(h, 576, ln2_w + l * D_, ln2_b + l * D_, ybuf);
    for (int c = 0; c < NCHUNK; ++c) {
      long off = (long)c * MC_;
      gemm_bt<2><<<dim3(FF_ / 64, MC_ / 256), 256, 0, stream>>>(
          ybuf + off * D_, w1_l, 2304, 576, fc1_b + l * FF_, nullptr, cbuf, nullptr, 0);
      gemm_bt<1><<<dim3(576 / 64, MC_ / 256), 256, 0, stream>>>(
          cbuf, w2_l, 576, 2304, fc2_b + l * D_, h + off * D_, nullptr, nullptr, 0);
    }
  }
  // final LN on CLS tokens only (token stride 31*576), then head
  ln_kernel<<<1024 / 4, 256, 0, stream>>>(h, (long)N_ * 576, norm_w, norm_b, cls);
  gemm_bt<3><<<dim3(1024 / 64, 1024 / 256), 256, 0, stream>>>(
      cls, whead, 1024, 576, head_b, nullptr, nullptr, (float*)d_out, NC_);
}

// Round 7
// 9338.517 us; speedup vs baseline: 1.2356x; 1.2356x over previous
//
#include <hip/hip_runtime.h>
#include <stdint.h>

typedef unsigned short u16;
typedef __bf16 bf16x8 __attribute__((ext_vector_type(8)));
typedef float f32x4 __attribute__((ext_vector_type(4)));

#define B_   1024
#define N_   31
#define D_   576
#define H_   16
#define L_   12
#define DH_  36
#define FF_  2304
#define NC_  1000
#define M_   (B_*N_)          // 31744 tokens
#define NEG_ (-987654321.0f)

// ---------- helpers ----------
__device__ __forceinline__ u16 f2bfbits(float f) {
  uint32_t x = __builtin_bit_cast(uint32_t, f);
  x += 0x7fffu + ((x >> 16) & 1u);   // RNE
  return (u16)(x >> 16);
}
__device__ __forceinline__ float bfbits2f(u16 u) {
  return __builtin_bit_cast(float, (uint32_t)u << 16);
}
__device__ __forceinline__ float lo_bf(uint32_t w) {
  return __builtin_bit_cast(float, w << 16);
}
__device__ __forceinline__ float hi_bf(uint32_t w) {
  return __builtin_bit_cast(float, w & 0xffff0000u);
}

typedef __attribute__((address_space(1))) void gvoid_t;
typedef __attribute__((address_space(3))) void lvoid_t;
__device__ __forceinline__ void async16(void* lds, const void* g) {
  __builtin_amdgcn_global_load_lds((gvoid_t*)const_cast<void*>(g), (lvoid_t*)lds, 16, 0, 0);
}

// ---------- GEMM: C[M,N] = A[M,K](bf16) * Bw[N,K](bf16)^T  + epilogue ----------
// BM=256, BN=64, BK=32. 256 threads = 4 waves, wave w owns rows [w*64, w*64+64) x 64 cols.
// EPI: 0 = store bf16 (QKV)
//      1 = resid[r*N+c] += acc + bias[c]   (f32 in-place; outproj / FC2)
//      2 = store bf16 gelu(acc + bias[c])  (FC1)
//      3 = outf[r*Nreal+c] = acc + bias[c] if c < Nreal  (head, f32)
template<int EPI>
__global__ __launch_bounds__(256, 3)
void gemm_bt(const u16* __restrict__ A, const u16* __restrict__ Bw,
             int N, int K,
             const float* __restrict__ bias,
             float* __restrict__ resid,
             u16* __restrict__ outb,
             float* __restrict__ outf, int Nreal)
{
  __shared__ alignas(16) u16 As[256 * 32];   // 16 KB
  __shared__ alignas(16) u16 Bs[64 * 32];    // 4 KB

  const int t    = threadIdx.x;
  const int wave = t >> 6;
  const int lane = t & 63;
  const int mBase = blockIdx.y * 256;
  const int nBase = blockIdx.x * 64;

  const int tr = t >> 2;          // 0..63 staging row within issue
  const int tc = (t & 3) * 8;     // staging col (elements)

  const int fr = lane & 15;
  const int fk = (lane >> 4) * 8;
  const u16* aBase = &As[(wave * 64 + fr) * 32 + fk];
  const u16* bBase = &Bs[fr * 32 + fk];

  f32x4 acc[4][4] = {};

  for (int k0 = 0; k0 < K; k0 += 32) {
    // stage A tile (256x32) : 4 issues, and B tile (64x32) : 1 issue
    #pragma unroll
    for (int i = 0; i < 4; ++i) {
      int row = i * 64 + tr;
      async16(&As[row * 32 + tc], A + (long)(mBase + row) * K + k0 + tc);
    }
    async16(&Bs[tr * 32 + tc], Bw + (long)(nBase + tr) * K + k0 + tc);
    asm volatile("s_waitcnt vmcnt(0)" ::: "memory");
    __syncthreads();

    bf16x8 af[4], bf_[4];
    #pragma unroll
    for (int m = 0; m < 4; ++m) af[m]  = *(const bf16x8*)(aBase + m * 16 * 32);
    #pragma unroll
    for (int n = 0; n < 4; ++n) bf_[n] = *(const bf16x8*)(bBase + n * 16 * 32);
    #pragma unroll
    for (int m = 0; m < 4; ++m)
      #pragma unroll
      for (int n = 0; n < 4; ++n)
        acc[m][n] = __builtin_amdgcn_mfma_f32_16x16x32_bf16(af[m], bf_[n], acc[m][n], 0, 0, 0);
    __syncthreads();
  }

  // epilogue: D layout col = lane&15, row = (lane>>4)*4 + reg  [m89-verified]
  const int fq = lane >> 4;
  #pragma unroll
  for (int m = 0; m < 4; ++m) {
    int gr0 = mBase + wave * 64 + m * 16 + fq * 4;
    #pragma unroll
    for (int n = 0; n < 4; ++n) {
      int gc = nBase + n * 16 + fr;
      #pragma unroll
      for (int r = 0; r < 4; ++r) {
        long gr = gr0 + r;
        float v = acc[m][n][r];
        if (EPI == 0) {
          outb[gr * N + gc] = f2bfbits(v);
        } else if (EPI == 1) {
          long idx = gr * N + gc;
          resid[idx] = resid[idx] + v + bias[gc];
        } else if (EPI == 2) {
          float x = v + bias[gc];
          float g = 0.5f * x * (1.0f + erff(x * 0.70710678118654752f));
          outb[gr * N + gc] = f2bfbits(g);
        } else {
          if (gc < Nreal) outf[gr * Nreal + gc] = v + bias[gc];
        }
      }
    }
  }
}

// ---------- LayerNorm: one wave per token (D=576 = 64 lanes * 9) ----------
__global__ __launch_bounds__(256)
void ln_kernel(const float* __restrict__ x, long tokStride,
               const float* __restrict__ w, const float* __restrict__ b,
               u16* __restrict__ y)
{
  int tok  = blockIdx.x * 4 + (threadIdx.x >> 6);
  int lane = threadIdx.x & 63;
  const float* row = x + (long)tok * tokStride;
  float v[9]; float s = 0.f, sq = 0.f;
  #pragma unroll
  for (int j = 0; j < 9; ++j) { v[j] = row[lane + j * 64]; s += v[j]; sq += v[j] * v[j]; }
  #pragma unroll
  for (int o = 32; o; o >>= 1) { s += __shfl_xor(s, o); sq += __shfl_xor(sq, o); }
  float mean = s * (1.f / 576.f);
  float var  = sq * (1.f / 576.f) - mean * mean;
  float inv  = rsqrtf(var + 1e-5f);
  u16* yr = y + (long)tok * 576;
  #pragma unroll
  for (int j = 0; j < 9; ++j) {
    int c = lane + j * 64;
    yr[c] = f2bfbits((v[j] - mean) * inv * w[c] + b[c]);
  }
}

// ---------- Attention: one wave per (local b, h). N=31, DH=36. diag masked. ----------
// qkv: [BCc*31, 1728] chunk, o: [BCc*31, 576] chunk
__global__ __launch_bounds__(256)
void attn_kernel(const u16* __restrict__ qkv, u16* __restrict__ o,
                 const float* __restrict__ scale)
{
  __shared__ float kls[4][N_ * DH_];
  __shared__ float vls[4][N_ * DH_];
  int wave = threadIdx.x >> 6, lane = threadIdx.x & 63;
  int bh = blockIdx.x * 4 + wave;
  int b  = bh >> 4, h = bh & 15;
  long base = (long)b * N_ * 1728 + h * DH_;

  // stage K,V rows (31 x 36 bf16 each) as f32 into LDS; 558 dword loads each
  for (int u = lane; u < 558; u += 64) {
    int row = u / 18, c = (u % 18) * 2;
    uint32_t kw = *(const uint32_t*)(qkv + base + 576  + (long)row * 1728 + c);
    uint32_t vw = *(const uint32_t*)(qkv + base + 1152 + (long)row * 1728 + c);
    kls[wave][row * 36 + c]     = lo_bf(kw);
    kls[wave][row * 36 + c + 1] = hi_bf(kw);
    vls[wave][row * 36 + c]     = lo_bf(vw);
    vls[wave][row * 36 + c + 1] = hi_bf(vw);
  }
  __syncthreads();

  // 2 lanes per query row: lane = 2*i + p, p splits d into halves of 18
  int i0 = lane >> 1, p = lane & 1;
  int i  = i0 > 30 ? 30 : i0;
  float qv[18];
  const u16* qrow = qkv + base + (long)i * 1728 + p * 18;
  #pragma unroll
  for (int d = 0; d < 18; ++d) qv[d] = bfbits2f(qrow[d]);

  float s[31];
  #pragma unroll
  for (int j = 0; j < 31; ++j) {
    float a = 0.f;
    const float* kr = &kls[wave][j * 36 + p * 18];
    #pragma unroll
    for (int d = 0; d < 18; ++d) a += qv[d] * kr[d];
    a += __shfl_xor(a, 1);           // combine the two d-halves
    s[j] = a;
  }
  float sc = scale[h];
  float mx = -1e30f;
  #pragma unroll
  for (int j = 0; j < 31; ++j) { s[j] = (j == i) ? NEG_ : s[j] * sc; mx = fmaxf(mx, s[j]); }
  float sum = 0.f;
  #pragma unroll
  for (int j = 0; j < 31; ++j) { s[j] = expf(s[j] - mx); sum += s[j]; }
  float inv = 1.f / sum;

  #pragma unroll
  for (int d = 0; d < 18; ++d) {
    float a = 0.f;
    #pragma unroll
    for (int j = 0; j < 31; ++j) a += s[j] * vls[wave][j * 36 + p * 18 + d];
    if (i0 < 31)
      o[(long)(b * N_ + i0) * 576 + h * DH_ + p * 18 + d] = f2bfbits(a * inv);
  }
}

// ---------- per-layer weight conversion: all 4 matrices in one kernel ----------
// segments (float4 units): qkv 248832 | out 82944 | fc1 331776 | fc2 331776 -> total 995328
__global__ void cvt_layer(const float4* __restrict__ s0, const float4* __restrict__ s1,
                          const float4* __restrict__ s2, const float4* __restrict__ s3,
                          u16* __restrict__ d0, u16* __restrict__ d1,
                          u16* __restrict__ d2, u16* __restrict__ d3)
{
  int idx = blockIdx.x * 256 + threadIdx.x;   // < 995328
  const float4* s; u16* d; int off;
  if (idx < 248832)      { s = s0; d = d0; off = idx; }
  else if (idx < 331776) { s = s1; d = d1; off = idx - 248832; }
  else if (idx < 663552) { s = s2; d = d2; off = idx - 331776; }
  else                   { s = s3; d = d3; off = idx - 663552; }
  float4 v = s[off];
  ushort4 r;
  r.x = f2bfbits(v.x); r.y = f2bfbits(v.y); r.z = f2bfbits(v.z); r.w = f2bfbits(v.w);
  *(ushort4*)(d + (long)off * 4) = r;
}

// head_w (1000x576) -> bf16 padded to 1024 rows (zeros)
__global__ void pad_head(const float* __restrict__ hw, u16* __restrict__ out)
{
  int idx = blockIdx.x * 256 + threadIdx.x;   // < 1024*576
  int row = idx / 576;
  out[idx] = (row < NC_) ? f2bfbits(hw[idx]) : (u16)0;
}

// ---------- launch ----------
extern "C" void kernel_launch(void* const* d_in, const int* in_sizes, int n_in,
                              void* d_out, int out_size, void* d_ws, size_t ws_size,
                              hipStream_t stream)
{
  (void)in_sizes; (void)n_in; (void)out_size;
  const float* x      = (const float*)d_in[0];
  const float* qkv_w  = (const float*)d_in[1];
  const float* scale  = (const float*)d_in[2];
  const float* out_w  = (const float*)d_in[3];
  const float* out_b  = (const float*)d_in[4];
  const float* ln1_w  = (const float*)d_in[5];
  const float* ln1_b  = (const float*)d_in[6];
  const float* ln2_w  = (const float*)d_in[7];
  const float* ln2_b  = (const float*)d_in[8];
  const float* fc1_w  = (const float*)d_in[9];
  const float* fc1_b  = (const float*)d_in[10];
  const float* fc2_w  = (const float*)d_in[11];
  const float* fc2_b  = (const float*)d_in[12];
  const float* norm_w = (const float*)d_in[13];
  const float* norm_b = (const float*)d_in[14];
  const float* head_w = (const float*)d_in[15];
  const float* head_b = (const float*)d_in[16];

  // ---- runtime chunk selection from ws_size (constant per harness -> graph-safe) ----
  auto al = [](size_t b) { return (b + 255) & ~(size_t)255; };
  const size_t fixed = al((size_t)M_ * D_ * 4) + al((size_t)M_ * D_ * 2)
                     + al((size_t)1728 * D_ * 2) + al((size_t)D_ * D_ * 2)
                     + al((size_t)FF_ * D_ * 2) + al((size_t)D_ * FF_ * 2)
                     + 2 * al((size_t)1024 * D_ * 2);
  const size_t cbuf2 = al((size_t)(M_ / 2) * FF_ * 2);   // 73.1 MB
  const int nch = (ws_size >= fixed + cbuf2) ? 2 : 4;    // 2-chunk (~201MB) or proven 4-chunk (~165MB)
  const int MC  = M_ / nch;                               // rows/chunk, multiple of 256
  const int BCc = B_ / nch;

  char* p = (char*)d_ws;
  auto take = [&](size_t bytes) { char* r = p; p += (bytes + 255) & ~(size_t)255; return r; };
  float* h    = (float*)take((size_t)M_ * D_ * 4);          // residual stream f32
  u16*   ybuf = (u16*)take((size_t)M_ * D_ * 2);            // LN out / attn out
  u16*   cbuf = (u16*)take((size_t)MC * FF_ * 2);           // chunk qkv / mlp mid
  u16*   wq_l = (u16*)take((size_t)1728 * D_ * 2);          // per-layer bf16 weights
  u16*   wo_l = (u16*)take((size_t)D_ * D_ * 2);
  u16*   w1_l = (u16*)take((size_t)FF_ * D_ * 2);
  u16*   w2_l = (u16*)take((size_t)D_ * FF_ * 2);
  u16*   whead = (u16*)take((size_t)1024 * D_ * 2);
  u16*   cls   = (u16*)take((size_t)1024 * D_ * 2);

  pad_head<<<(1024 * 576) / 256, 256, 0, stream>>>(head_w, whead);
  hipMemcpyAsync(h, x, (size_t)M_ * D_ * 4, hipMemcpyDeviceToDevice, stream);

  for (int l = 0; l < L_; ++l) {
    cvt_layer<<<3888, 256, 0, stream>>>(
        (const float4*)(qkv_w + (size_t)l * 1728 * D_),
        (const float4*)(out_w + (size_t)l * D_ * D_),
        (const float4*)(fc1_w + (size_t)l * FF_ * D_),
        (const float4*)(fc2_w + (size_t)l * D_ * FF_),
        wq_l, wo_l, w1_l, w2_l);

    // LN1 -> per-chunk {QKV, attn} -> ONE full-M outproj (util 54% -> 87%)
    ln_kernel<<<M_ / 4, 256, 0, stream>>>(h, 576, ln1_w + l * D_, ln1_b + l * D_, ybuf);
    for (int c = 0; c < nch; ++c) {
      long off = (long)c * MC;
      gemm_bt<0><<<dim3(1728 / 64, MC / 256), 256, 0, stream>>>(
          ybuf + off * D_, wq_l, 1728, 576, nullptr, nullptr, cbuf, nullptr, 0);
      attn_kernel<<<(BCc * H_) / 4, 256, 0, stream>>>(cbuf, ybuf + off * D_, scale + l * H_);
    }
    gemm_bt<1><<<dim3(576 / 64, M_ / 256), 256, 0, stream>>>(
        ybuf, wo_l, 576, 576, out_b + l * D_, h, nullptr, nullptr, 0);

    // LN2 -> per-chunk {FC1+gelu, FC2+residual}
    ln_kernel<<<M_ / 4, 256, 0, stream>>>(h, 576, ln2_w + l * D_, ln2_b + l * D_, ybuf);
    for (int c = 0; c < nch; ++c) {
      long off = (long)c * MC;
      gemm_bt<2><<<dim3(FF_ / 64, MC / 256), 256, 0, stream>>>(
          ybuf + off * D_, w1_l, 2304, 576, fc1_b + l * FF_, nullptr, cbuf, nullptr, 0);
      gemm_bt<1><<<dim3(576 / 64, MC / 256), 256, 0, stream>>>(
          cbuf, w2_l, 576, 2304, fc2_b + l * D_, h + off * D_, nullptr, nullptr, 0);
    }
  }
  // final LN on CLS tokens only (token stride 31*576), then head
  ln_kernel<<<1024 / 4, 256, 0, stream>>>(h, (long)N_ * 576, norm_w, norm_b, cls);
  gemm_bt<3><<<dim3(1024 / 64, 1024 / 256), 256, 0, stream>>>(
      cls, whead, 1024, 576, head_b, nullptr, nullptr, (float*)d_out, NC_);
}

// Round 8
// 7625.257 us; speedup vs baseline: 1.5133x; 1.2247x over previous
//
#include <hip/hip_runtime.h>
#include <stdint.h>

typedef unsigned short u16;
typedef __bf16 bf16x8 __attribute__((ext_vector_type(8)));
typedef float f32x4 __attribute__((ext_vector_type(4)));

#define B_   1024
#define N_   31
#define D_   576
#define H_   16
#define L_   12
#define DH_  36
#define FF_  2304
#define NC_  1000
#define M_   (B_*N_)          // 31744 tokens
#define NEG_ (-987654321.0f)

// ---------- helpers ----------
__device__ __forceinline__ u16 f2bfbits(float f) {
  uint32_t x = __builtin_bit_cast(uint32_t, f);
  x += 0x7fffu + ((x >> 16) & 1u);   // RNE
  return (u16)(x >> 16);
}
__device__ __forceinline__ float bfbits2f(u16 u) {
  return __builtin_bit_cast(float, (uint32_t)u << 16);
}
__device__ __forceinline__ float lo_bf(uint32_t w) {
  return __builtin_bit_cast(float, w << 16);
}
__device__ __forceinline__ float hi_bf(uint32_t w) {
  return __builtin_bit_cast(float, w & 0xffff0000u);
}

typedef __attribute__((address_space(1))) void gvoid_t;
typedef __attribute__((address_space(3))) void lvoid_t;
__device__ __forceinline__ void async16(void* lds, const void* g) {
  __builtin_amdgcn_global_load_lds((gvoid_t*)const_cast<void*>(g), (lvoid_t*)lds, 16, 0, 0);
}

// ---------- GEMM: C[M,N] = A[M,K](bf16) * Bw[N,K](bf16)^T  + epilogue ----------
// BM=256, BN=64, BK=32. 256 threads = 4 waves, wave w owns rows [w*64, w*64+64) x 64 cols.
// XCD-chunked bijective swizzle (m204): consecutive flat tiles (x-fastest, which
// share the same 256-row A panel) are remapped onto ONE XCD so the panel is
// fetched into that XCD's L2 once instead of once per XCD (FETCH was 3-4.5x ideal).
// EPI: 0 = store bf16 (QKV)
//      1 = resid[r*N+c] += acc + bias[c]   (f32 in-place; outproj / FC2)
//      2 = store bf16 gelu(acc + bias[c])  (FC1)
//      3 = outf[r*Nreal+c] = acc + bias[c] if c < Nreal  (head, f32)
template<int EPI>
__global__ __launch_bounds__(256, 3)
void gemm_bt(const u16* __restrict__ A, const u16* __restrict__ Bw,
             int N, int K,
             const float* __restrict__ bias,
             float* __restrict__ resid,
             u16* __restrict__ outb,
             float* __restrict__ outf, int Nreal)
{
  __shared__ alignas(16) u16 As[256 * 32];   // 16 KB
  __shared__ alignas(16) u16 Bs[64 * 32];    // 4 KB

  const int t    = threadIdx.x;
  const int wave = t >> 6;
  const int lane = t & 63;

  // bijective XCD swizzle: hardware assigns orig -> XCD (orig % 8); give XCD x
  // the contiguous tile range so A-panel reuse happens within one L2.
  const int nwg  = gridDim.x * gridDim.y;
  const int orig = blockIdx.y * gridDim.x + blockIdx.x;
  const int q = nwg >> 3, r = nwg & 7, xc = orig & 7, o = orig >> 3;
  const int wid = (xc < r ? xc * (q + 1) : r * (q + 1) + (xc - r) * q) + o;
  const int mBase = (wid / gridDim.x) * 256;
  const int nBase = (wid % gridDim.x) * 64;

  const int tr = t >> 2;          // 0..63 staging row within issue
  const int tc = (t & 3) * 8;     // staging col (elements)

  const int fr = lane & 15;
  const int fk = (lane >> 4) * 8;
  const u16* aBase = &As[(wave * 64 + fr) * 32 + fk];
  const u16* bBase = &Bs[fr * 32 + fk];

  f32x4 acc[4][4] = {};

  for (int k0 = 0; k0 < K; k0 += 32) {
    // stage A tile (256x32) : 4 issues, and B tile (64x32) : 1 issue
    #pragma unroll
    for (int i = 0; i < 4; ++i) {
      int row = i * 64 + tr;
      async16(&As[row * 32 + tc], A + (long)(mBase + row) * K + k0 + tc);
    }
    async16(&Bs[tr * 32 + tc], Bw + (long)(nBase + tr) * K + k0 + tc);
    asm volatile("s_waitcnt vmcnt(0)" ::: "memory");
    __syncthreads();

    bf16x8 af[4], bf_[4];
    #pragma unroll
    for (int m = 0; m < 4; ++m) af[m]  = *(const bf16x8*)(aBase + m * 16 * 32);
    #pragma unroll
    for (int n = 0; n < 4; ++n) bf_[n] = *(const bf16x8*)(bBase + n * 16 * 32);
    #pragma unroll
    for (int m = 0; m < 4; ++m)
      #pragma unroll
      for (int n = 0; n < 4; ++n)
        acc[m][n] = __builtin_amdgcn_mfma_f32_16x16x32_bf16(af[m], bf_[n], acc[m][n], 0, 0, 0);
    __syncthreads();
  }

  // epilogue: D layout col = lane&15, row = (lane>>4)*4 + reg  [m89-verified]
  const int fq = lane >> 4;
  #pragma unroll
  for (int m = 0; m < 4; ++m) {
    int gr0 = mBase + wave * 64 + m * 16 + fq * 4;
    #pragma unroll
    for (int n = 0; n < 4; ++n) {
      int gc = nBase + n * 16 + fr;
      #pragma unroll
      for (int r2 = 0; r2 < 4; ++r2) {
        long gr = gr0 + r2;
        float v = acc[m][n][r2];
        if (EPI == 0) {
          outb[gr * N + gc] = f2bfbits(v);
        } else if (EPI == 1) {
          long idx = gr * N + gc;
          resid[idx] = resid[idx] + v + bias[gc];
        } else if (EPI == 2) {
          float x = v + bias[gc];
          float g = 0.5f * x * (1.0f + erff(x * 0.70710678118654752f));
          outb[gr * N + gc] = f2bfbits(g);
        } else {
          if (gc < Nreal) outf[gr * Nreal + gc] = v + bias[gc];
        }
      }
    }
  }
}

// ---------- LayerNorm: one wave per token (D=576 = 64 lanes * 9) ----------
__global__ __launch_bounds__(256)
void ln_kernel(const float* __restrict__ x, long tokStride,
               const float* __restrict__ w, const float* __restrict__ b,
               u16* __restrict__ y)
{
  int tok  = blockIdx.x * 4 + (threadIdx.x >> 6);
  int lane = threadIdx.x & 63;
  const float* row = x + (long)tok * tokStride;
  float v[9]; float s = 0.f, sq = 0.f;
  #pragma unroll
  for (int j = 0; j < 9; ++j) { v[j] = row[lane + j * 64]; s += v[j]; sq += v[j] * v[j]; }
  #pragma unroll
  for (int o = 32; o; o >>= 1) { s += __shfl_xor(s, o); sq += __shfl_xor(sq, o); }
  float mean = s * (1.f / 576.f);
  float var  = sq * (1.f / 576.f) - mean * mean;
  float inv  = rsqrtf(var + 1e-5f);
  u16* yr = y + (long)tok * 576;
  #pragma unroll
  for (int j = 0; j < 9; ++j) {
    int c = lane + j * 64;
    yr[c] = f2bfbits((v[j] - mean) * inv * w[c] + b[c]);
  }
}

// ---------- Attention: one wave per (local b, h). N=31, DH=36. diag masked. ----------
// qkv: [BCc*31, 1728] chunk, o: [BCc*31, 576] chunk
__global__ __launch_bounds__(256)
void attn_kernel(const u16* __restrict__ qkv, u16* __restrict__ o,
                 const float* __restrict__ scale)
{
  __shared__ float kls[4][N_ * DH_];
  __shared__ float vls[4][N_ * DH_];
  int wave = threadIdx.x >> 6, lane = threadIdx.x & 63;
  int bh = blockIdx.x * 4 + wave;
  int b  = bh >> 4, h = bh & 15;
  long base = (long)b * N_ * 1728 + h * DH_;

  // stage K,V rows (31 x 36 bf16 each) as f32 into LDS; 558 dword loads each
  for (int u = lane; u < 558; u += 64) {
    int row = u / 18, c = (u % 18) * 2;
    uint32_t kw = *(const uint32_t*)(qkv + base + 576  + (long)row * 1728 + c);
    uint32_t vw = *(const uint32_t*)(qkv + base + 1152 + (long)row * 1728 + c);
    kls[wave][row * 36 + c]     = lo_bf(kw);
    kls[wave][row * 36 + c + 1] = hi_bf(kw);
    vls[wave][row * 36 + c]     = lo_bf(vw);
    vls[wave][row * 36 + c + 1] = hi_bf(vw);
  }
  __syncthreads();

  // 2 lanes per query row: lane = 2*i + p, p splits d into halves of 18
  int i0 = lane >> 1, p = lane & 1;
  int i  = i0 > 30 ? 30 : i0;
  float qv[18];
  const u16* qrow = qkv + base + (long)i * 1728 + p * 18;
  #pragma unroll
  for (int d = 0; d < 18; ++d) qv[d] = bfbits2f(qrow[d]);

  float s[31];
  #pragma unroll
  for (int j = 0; j < 31; ++j) {
    float a = 0.f;
    const float* kr = &kls[wave][j * 36 + p * 18];
    #pragma unroll
    for (int d = 0; d < 18; ++d) a += qv[d] * kr[d];
    a += __shfl_xor(a, 1);           // combine the two d-halves
    s[j] = a;
  }
  float sc = scale[h];
  float mx = -1e30f;
  #pragma unroll
  for (int j = 0; j < 31; ++j) { s[j] = (j == i) ? NEG_ : s[j] * sc; mx = fmaxf(mx, s[j]); }
  float sum = 0.f;
  #pragma unroll
  for (int j = 0; j < 31; ++j) { s[j] = expf(s[j] - mx); sum += s[j]; }
  float inv = 1.f / sum;

  #pragma unroll
  for (int d = 0; d < 18; ++d) {
    float a = 0.f;
    #pragma unroll
    for (int j = 0; j < 31; ++j) a += s[j] * vls[wave][j * 36 + p * 18 + d];
    if (i0 < 31)
      o[(long)(b * N_ + i0) * 576 + h * DH_ + p * 18 + d] = f2bfbits(a * inv);
  }
}

// ---------- per-layer weight conversion: all 4 matrices in one kernel ----------
// segments (float4 units): qkv 248832 | out 82944 | fc1 331776 | fc2 331776 -> total 995328
__global__ void cvt_layer(const float4* __restrict__ s0, const float4* __restrict__ s1,
                          const float4* __restrict__ s2, const float4* __restrict__ s3,
                          u16* __restrict__ d0, u16* __restrict__ d1,
                          u16* __restrict__ d2, u16* __restrict__ d3)
{
  int idx = blockIdx.x * 256 + threadIdx.x;   // < 995328
  const float4* s; u16* d; int off;
  if (idx < 248832)      { s = s0; d = d0; off = idx; }
  else if (idx < 331776) { s = s1; d = d1; off = idx - 248832; }
  else if (idx < 663552) { s = s2; d = d2; off = idx - 331776; }
  else                   { s = s3; d = d3; off = idx - 663552; }
  float4 v = s[off];
  ushort4 r;
  r.x = f2bfbits(v.x); r.y = f2bfbits(v.y); r.z = f2bfbits(v.z); r.w = f2bfbits(v.w);
  *(ushort4*)(d + (long)off * 4) = r;
}

// head_w (1000x576) -> bf16 padded to 1024 rows (zeros)
__global__ void pad_head(const float* __restrict__ hw, u16* __restrict__ out)
{
  int idx = blockIdx.x * 256 + threadIdx.x;   // < 1024*576
  int row = idx / 576;
  out[idx] = (row < NC_) ? f2bfbits(hw[idx]) : (u16)0;
}

// ---------- launch ----------
extern "C" void kernel_launch(void* const* d_in, const int* in_sizes, int n_in,
                              void* d_out, int out_size, void* d_ws, size_t ws_size,
                              hipStream_t stream)
{
  (void)in_sizes; (void)n_in; (void)out_size;
  const float* x      = (const float*)d_in[0];
  const float* qkv_w  = (const float*)d_in[1];
  const float* scale  = (const float*)d_in[2];
  const float* out_w  = (const float*)d_in[3];
  const float* out_b  = (const float*)d_in[4];
  const float* ln1_w  = (const float*)d_in[5];
  const float* ln1_b  = (const float*)d_in[6];
  const float* ln2_w  = (const float*)d_in[7];
  const float* ln2_b  = (const float*)d_in[8];
  const float* fc1_w  = (const float*)d_in[9];
  const float* fc1_b  = (const float*)d_in[10];
  const float* fc2_w  = (const float*)d_in[11];
  const float* fc2_b  = (const float*)d_in[12];
  const float* norm_w = (const float*)d_in[13];
  const float* norm_b = (const float*)d_in[14];
  const float* head_w = (const float*)d_in[15];
  const float* head_b = (const float*)d_in[16];

  // ---- runtime chunk selection from ws_size (constant per harness -> graph-safe) ----
  auto al = [](size_t b) { return (b + 255) & ~(size_t)255; };
  const size_t fixed = al((size_t)M_ * D_ * 4) + al((size_t)M_ * D_ * 2)
                     + al((size_t)1728 * D_ * 2) + al((size_t)D_ * D_ * 2)
                     + al((size_t)FF_ * D_ * 2) + al((size_t)D_ * FF_ * 2)
                     + 2 * al((size_t)1024 * D_ * 2);
  const size_t cbuf2 = al((size_t)(M_ / 2) * FF_ * 2);   // 73.1 MB
  const int nch = (ws_size >= fixed + cbuf2) ? 2 : 4;    // 2-chunk (~201MB) or proven 4-chunk (~165MB)
  const int MC  = M_ / nch;                               // rows/chunk, multiple of 256
  const int BCc = B_ / nch;

  char* p = (char*)d_ws;
  auto take = [&](size_t bytes) { char* r = p; p += (bytes + 255) & ~(size_t)255; return r; };
  float* h    = (float*)take((size_t)M_ * D_ * 4);          // residual stream f32
  u16*   ybuf = (u16*)take((size_t)M_ * D_ * 2);            // LN out / attn out
  u16*   cbuf = (u16*)take((size_t)MC * FF_ * 2);           // chunk qkv / mlp mid
  u16*   wq_l = (u16*)take((size_t)1728 * D_ * 2);          // per-layer bf16 weights
  u16*   wo_l = (u16*)take((size_t)D_ * D_ * 2);
  u16*   w1_l = (u16*)take((size_t)FF_ * D_ * 2);
  u16*   w2_l = (u16*)take((size_t)D_ * FF_ * 2);
  u16*   whead = (u16*)take((size_t)1024 * D_ * 2);
  u16*   cls   = (u16*)take((size_t)1024 * D_ * 2);

  pad_head<<<(1024 * 576) / 256, 256, 0, stream>>>(head_w, whead);
  hipMemcpyAsync(h, x, (size_t)M_ * D_ * 4, hipMemcpyDeviceToDevice, stream);

  for (int l = 0; l < L_; ++l) {
    cvt_layer<<<3888, 256, 0, stream>>>(
        (const float4*)(qkv_w + (size_t)l * 1728 * D_),
        (const float4*)(out_w + (size_t)l * D_ * D_),
        (const float4*)(fc1_w + (size_t)l * FF_ * D_),
        (const float4*)(fc2_w + (size_t)l * D_ * FF_),
        wq_l, wo_l, w1_l, w2_l);

    // LN1 -> per-chunk {QKV, attn} -> ONE full-M outproj
    ln_kernel<<<M_ / 4, 256, 0, stream>>>(h, 576, ln1_w + l * D_, ln1_b + l * D_, ybuf);
    for (int c = 0; c < nch; ++c) {
      long off = (long)c * MC;
      gemm_bt<0><<<dim3(1728 / 64, MC / 256), 256, 0, stream>>>(
          ybuf + off * D_, wq_l, 1728, 576, nullptr, nullptr, cbuf, nullptr, 0);
      attn_kernel<<<(BCc * H_) / 4, 256, 0, stream>>>(cbuf, ybuf + off * D_, scale + l * H_);
    }
    gemm_bt<1><<<dim3(576 / 64, M_ / 256), 256, 0, stream>>>(
        ybuf, wo_l, 576, 576, out_b + l * D_, h, nullptr, nullptr, 0);

    // LN2 -> per-chunk {FC1+gelu, FC2+residual}
    ln_kernel<<<M_ / 4, 256, 0, stream>>>(h, 576, ln2_w + l * D_, ln2_b + l * D_, ybuf);
    for (int c = 0; c < nch; ++c) {
      long off = (long)c * MC;
      gemm_bt<2><<<dim3(FF_ / 64, MC / 256), 256, 0, stream>>>(
          ybuf + off * D_, w1_l, 2304, 576, fc1_b + l * FF_, nullptr, cbuf, nullptr, 0);
      gemm_bt<1><<<dim3(576 / 64, MC / 256), 256, 0, stream>>>(
          cbuf, w2_l, 576, 2304, fc2_b + l * D_, h + off * D_, nullptr, nullptr, 0);
    }
  }
  // final LN on CLS tokens only (token stride 31*576), then head
  ln_kernel<<<1024 / 4, 256, 0, stream>>>(h, (long)N_ * 576, norm_w, norm_b, cls);
  gemm_bt<3><<<dim3(1024 / 64, 1024 / 256), 256, 0, stream>>>(
      cls, whead, 1024, 576, head_b, nullptr, nullptr, (float*)d_out, NC_);
}

// Round 11
// 7586.065 us; speedup vs baseline: 1.5211x; 1.0052x over previous
//
#include <hip/hip_runtime.h>
#include <stdint.h>

typedef unsigned short u16;
typedef __bf16 bf16x8 __attribute__((ext_vector_type(8)));
typedef float f32x4 __attribute__((ext_vector_type(4)));

#define B_   1024
#define N_   31
#define D_   576
#define H_   16
#define L_   12
#define DH_  36
#define FF_  2304
#define NC_  1000
#define M_   (B_*N_)          // 31744 tokens
#define NEG_ (-987654321.0f)

// ---------- helpers ----------
__device__ __forceinline__ u16 f2bfbits(float f) {
  uint32_t x = __builtin_bit_cast(uint32_t, f);
  x += 0x7fffu + ((x >> 16) & 1u);   // RNE
  return (u16)(x >> 16);
}
__device__ __forceinline__ float bfbits2f(u16 u) {
  return __builtin_bit_cast(float, (uint32_t)u << 16);
}
__device__ __forceinline__ float lo_bf(uint32_t w) {
  return __builtin_bit_cast(float, w << 16);
}
__device__ __forceinline__ float hi_bf(uint32_t w) {
  return __builtin_bit_cast(float, w & 0xffff0000u);
}

typedef __attribute__((address_space(1))) void gvoid_t;
typedef __attribute__((address_space(3))) void lvoid_t;
__device__ __forceinline__ void async16(void* lds, const void* g) {
  __builtin_amdgcn_global_load_lds((gvoid_t*)const_cast<void*>(g), (lvoid_t*)lds, 16, 0, 0);
}

// ---------- GEMM: C[M,N] = A[M,K](bf16) * Bw[N,K](bf16)^T  + epilogue ----------
// BK=32, BN=64, 256 threads = 4 waves.
//   BM=256: wave w owns rows [w*64, w*64+64) x all 64 cols (acc 4x4)
//   BM=128: wave (w>>1) owns 64 rows, (w&1) owns 32-col half (acc 4x2) — for
//           N=576 GEMMs whose grids were starved at 2.2 blocks/CU.
// LDS slot swizzle (both-sides involution, rule #21): rows are 64B = 16 banks,
// so same-slot reads across 16 rows were 8-way bank conflicts (5.14M/dispatch).
// physical_slot = logical_slot ^ ((row>>1)&3) spreads 8 consecutive rows over
// 8 distinct banks -> 2 lanes/bank (free). Staging keeps LDS dest linear and
// pre-swizzles the GLOBAL source column; reads apply the same XOR.
// XCD-chunked bijective blockIdx swizzle (m204) keeps A-panel reuse in one L2.
// EPI: 0 = store bf16 (QKV)
//      1 = resid[r*N+c] += acc + bias[c]   (f32 in-place; outproj / FC2)
//      2 = store bf16 gelu(acc + bias[c])  (FC1)
//      3 = outf[r*Nreal+c] = acc + bias[c] if c < Nreal  (head, f32)
template<int EPI, int BM>
__global__ __launch_bounds__(256, 3)
void gemm_bt(const u16* __restrict__ A, const u16* __restrict__ Bw,
             int N, int K,
             const float* __restrict__ bias,
             float* __restrict__ resid,
             u16* __restrict__ outb,
             float* __restrict__ outf, int Nreal)
{
  constexpr int NF = (BM == 256) ? 4 : 2;        // n-fragments per wave
  __shared__ alignas(16) u16 As[BM * 32];
  __shared__ alignas(16) u16 Bs[64 * 32];

  const int t    = threadIdx.x;
  const int wave = t >> 6;
  const int lane = t & 63;

  // bijective XCD swizzle
  const int nwg  = gridDim.x * gridDim.y;
  const int orig = blockIdx.y * gridDim.x + blockIdx.x;
  const int q = nwg >> 3, r = nwg & 7, xc = orig & 7, o = orig >> 3;
  const int wid = (xc < r ? xc * (q + 1) : r * (q + 1) + (xc - r) * q) + o;
  const int mBase = (wid / gridDim.x) * BM;
  const int nBase = (wid % gridDim.x) * 64;

  const int wm   = (BM == 256) ? wave : (wave >> 1);
  const int wcol = (BM == 256) ? 0 : (wave & 1) * 32;

  const int tr = t >> 2;                          // staging row within issue
  const int tc = ((t & 3) ^ ((t >> 3) & 3)) * 8;  // PRE-SWIZZLED source col

  const int fr = lane & 15;
  const int fk = (((lane >> 4) ^ ((lane >> 1) & 3))) * 8;  // swizzled read slot
  const u16* aBase = &As[(wm * 64 + fr) * 32 + fk];
  const u16* bBase = &Bs[(wcol + fr) * 32 + fk];

  f32x4 acc[4][NF] = {};

  for (int k0 = 0; k0 < K; k0 += 32) {
    #pragma unroll
    for (int i = 0; i < BM / 64; ++i) {
      int row = i * 64 + tr;
      async16(&As[row * 32 + (t & 3) * 8], A + (long)(mBase + row) * K + k0 + tc);
    }
    async16(&Bs[tr * 32 + (t & 3) * 8], Bw + (long)(nBase + tr) * K + k0 + tc);
    asm volatile("s_waitcnt vmcnt(0)" ::: "memory");
    __syncthreads();

    bf16x8 af[4], bf_[NF];
    #pragma unroll
    for (int m = 0; m < 4; ++m) af[m]  = *(const bf16x8*)(aBase + m * 16 * 32);
    #pragma unroll
    for (int n = 0; n < NF; ++n) bf_[n] = *(const bf16x8*)(bBase + n * 16 * 32);
    #pragma unroll
    for (int m = 0; m < 4; ++m)
      #pragma unroll
      for (int n = 0; n < NF; ++n)
        acc[m][n] = __builtin_amdgcn_mfma_f32_16x16x32_bf16(af[m], bf_[n], acc[m][n], 0, 0, 0);
    __syncthreads();
  }

  // epilogue: D layout col = lane&15, row = (lane>>4)*4 + reg  [m89-verified]
  const int fq = lane >> 4;
  #pragma unroll
  for (int m = 0; m < 4; ++m) {
    int gr0 = mBase + wm * 64 + m * 16 + fq * 4;
    #pragma unroll
    for (int n = 0; n < NF; ++n) {
      int gc = nBase + wcol + n * 16 + fr;
      #pragma unroll
      for (int r2 = 0; r2 < 4; ++r2) {
        long gr = gr0 + r2;
        float v = acc[m][n][r2];
        if (EPI == 0) {
          outb[gr * N + gc] = f2bfbits(v);
        } else if (EPI == 1) {
          long idx = gr * N + gc;
          resid[idx] = resid[idx] + v + bias[gc];
        } else if (EPI == 2) {
          float x = v + bias[gc];
          float g = 0.5f * x * (1.0f + erff(x * 0.70710678118654752f));
          outb[gr * N + gc] = f2bfbits(g);
        } else {
          if (gc < Nreal) outf[gr * Nreal + gc] = v + bias[gc];
        }
      }
    }
  }
}

// ---------- LayerNorm: one wave per token (D=576 = 64 lanes * 9) ----------
__global__ __launch_bounds__(256)
void ln_kernel(const float* __restrict__ x, long tokStride,
               const float* __restrict__ w, const float* __restrict__ b,
               u16* __restrict__ y)
{
  int tok  = blockIdx.x * 4 + (threadIdx.x >> 6);
  int lane = threadIdx.x & 63;
  const float* row = x + (long)tok * tokStride;
  float v[9]; float s = 0.f, sq = 0.f;
  #pragma unroll
  for (int j = 0; j < 9; ++j) { v[j] = row[lane + j * 64]; s += v[j]; sq += v[j] * v[j]; }
  #pragma unroll
  for (int o = 32; o; o >>= 1) { s += __shfl_xor(s, o); sq += __shfl_xor(sq, o); }
  float mean = s * (1.f / 576.f);
  float var  = sq * (1.f / 576.f) - mean * mean;
  float inv  = rsqrtf(var + 1e-5f);
  u16* yr = y + (long)tok * 576;
  #pragma unroll
  for (int j = 0; j < 9; ++j) {
    int c = lane + j * 64;
    yr[c] = f2bfbits((v[j] - mean) * inv * w[c] + b[c]);
  }
}

// ---------- Attention: one wave per (local b, h). N=31, DH=36. diag masked. ----------
__global__ __launch_bounds__(256)
void attn_kernel(const u16* __restrict__ qkv, u16* __restrict__ o,
                 const float* __restrict__ scale)
{
  __shared__ float kls[4][N_ * DH_];
  __shared__ float vls[4][N_ * DH_];
  int wave = threadIdx.x >> 6, lane = threadIdx.x & 63;
  int bh = blockIdx.x * 4 + wave;
  int b  = bh >> 4, h = bh & 15;
  long base = (long)b * N_ * 1728 + h * DH_;

  for (int u = lane; u < 558; u += 64) {
    int row = u / 18, c = (u % 18) * 2;
    uint32_t kw = *(const uint32_t*)(qkv + base + 576  + (long)row * 1728 + c);
    uint32_t vw = *(const uint32_t*)(qkv + base + 1152 + (long)row * 1728 + c);
    kls[wave][row * 36 + c]     = lo_bf(kw);
    kls[wave][row * 36 + c + 1] = hi_bf(kw);
    vls[wave][row * 36 + c]     = lo_bf(vw);
    vls[wave][row * 36 + c + 1] = hi_bf(vw);
  }
  __syncthreads();

  int i0 = lane >> 1, p = lane & 1;
  int i  = i0 > 30 ? 30 : i0;
  float qv[18];
  const u16* qrow = qkv + base + (long)i * 1728 + p * 18;
  #pragma unroll
  for (int d = 0; d < 18; ++d) qv[d] = bfbits2f(qrow[d]);

  float s[31];
  #pragma unroll
  for (int j = 0; j < 31; ++j) {
    float a = 0.f;
    const float* kr = &kls[wave][j * 36 + p * 18];
    #pragma unroll
    for (int d = 0; d < 18; ++d) a += qv[d] * kr[d];
    a += __shfl_xor(a, 1);
    s[j] = a;
  }
  float sc = scale[h];
  float mx = -1e30f;
  #pragma unroll
  for (int j = 0; j < 31; ++j) { s[j] = (j == i) ? NEG_ : s[j] * sc; mx = fmaxf(mx, s[j]); }
  float sum = 0.f;
  #pragma unroll
  for (int j = 0; j < 31; ++j) { s[j] = expf(s[j] - mx); sum += s[j]; }
  float inv = 1.f / sum;

  #pragma unroll
  for (int d = 0; d < 18; ++d) {
    float a = 0.f;
    #pragma unroll
    for (int j = 0; j < 31; ++j) a += s[j] * vls[wave][j * 36 + p * 18 + d];
    if (i0 < 31)
      o[(long)(b * N_ + i0) * 576 + h * DH_ + p * 18 + d] = f2bfbits(a * inv);
  }
}

// ---------- per-layer weight conversion: all 4 matrices in one kernel ----------
__global__ void cvt_layer(const float4* __restrict__ s0, const float4* __restrict__ s1,
                          const float4* __restrict__ s2, const float4* __restrict__ s3,
                          u16* __restrict__ d0, u16* __restrict__ d1,
                          u16* __restrict__ d2, u16* __restrict__ d3)
{
  int idx = blockIdx.x * 256 + threadIdx.x;   // < 995328
  const float4* s; u16* d; int off;
  if (idx < 248832)      { s = s0; d = d0; off = idx; }
  else if (idx < 331776) { s = s1; d = d1; off = idx - 248832; }
  else if (idx < 663552) { s = s2; d = d2; off = idx - 331776; }
  else                   { s = s3; d = d3; off = idx - 663552; }
  float4 v = s[off];
  ushort4 r;
  r.x = f2bfbits(v.x); r.y = f2bfbits(v.y); r.z = f2bfbits(v.z); r.w = f2bfbits(v.w);
  *(ushort4*)(d + (long)off * 4) = r;
}

// head_w (1000x576) -> bf16 padded to 1024 rows (zeros)
__global__ void pad_head(const float* __restrict__ hw, u16* __restrict__ out)
{
  int idx = blockIdx.x * 256 + threadIdx.x;   // < 1024*576
  int row = idx / 576;
  out[idx] = (row < NC_) ? f2bfbits(hw[idx]) : (u16)0;
}

// ---------- launch ----------
extern "C" void kernel_launch(void* const* d_in, const int* in_sizes, int n_in,
                              void* d_out, int out_size, void* d_ws, size_t ws_size,
                              hipStream_t stream)
{
  (void)in_sizes; (void)n_in; (void)out_size;
  const float* x      = (const float*)d_in[0];
  const float* qkv_w  = (const float*)d_in[1];
  const float* scale  = (const float*)d_in[2];
  const float* out_w  = (const float*)d_in[3];
  const float* out_b  = (const float*)d_in[4];
  const float* ln1_w  = (const float*)d_in[5];
  const float* ln1_b  = (const float*)d_in[6];
  const float* ln2_w  = (const float*)d_in[7];
  const float* ln2_b  = (const float*)d_in[8];
  const float* fc1_w  = (const float*)d_in[9];
  const float* fc1_b  = (const float*)d_in[10];
  const float* fc2_w  = (const float*)d_in[11];
  const float* fc2_b  = (const float*)d_in[12];
  const float* norm_w = (const float*)d_in[13];
  const float* norm_b = (const float*)d_in[14];
  const float* head_w = (const float*)d_in[15];
  const float* head_b = (const float*)d_in[16];

  // ---- runtime chunk selection from ws_size (constant per harness -> graph-safe) ----
  auto al = [](size_t b) { return (b + 255) & ~(size_t)255; };
  const size_t fixed = al((size_t)M_ * D_ * 4) + al((size_t)M_ * D_ * 2)
                     + al((size_t)1728 * D_ * 2) + al((size_t)D_ * D_ * 2)
                     + al((size_t)FF_ * D_ * 2) + al((size_t)D_ * FF_ * 2)
                     + 2 * al((size_t)1024 * D_ * 2);
  const size_t cbuf2 = al((size_t)(M_ / 2) * FF_ * 2);   // 73.1 MB
  const int nch = (ws_size >= fixed + cbuf2) ? 2 : 4;
  const int MC  = M_ / nch;
  const int BCc = B_ / nch;

  char* p = (char*)d_ws;
  auto take = [&](size_t bytes) { char* r = p; p += (bytes + 255) & ~(size_t)255; return r; };
  float* h    = (float*)take((size_t)M_ * D_ * 4);
  u16*   ybuf = (u16*)take((size_t)M_ * D_ * 2);
  u16*   cbuf = (u16*)take((size_t)MC * FF_ * 2);
  u16*   wq_l = (u16*)take((size_t)1728 * D_ * 2);
  u16*   wo_l = (u16*)take((size_t)D_ * D_ * 2);
  u16*   w1_l = (u16*)take((size_t)FF_ * D_ * 2);
  u16*   w2_l = (u16*)take((size_t)D_ * FF_ * 2);
  u16*   whead = (u16*)take((size_t)1024 * D_ * 2);
  u16*   cls   = (u16*)take((size_t)1024 * D_ * 2);

  pad_head<<<(1024 * 576) / 256, 256, 0, stream>>>(head_w, whead);
  hipMemcpyAsync(h, x, (size_t)M_ * D_ * 4, hipMemcpyDeviceToDevice, stream);

  for (int l = 0; l < L_; ++l) {
    cvt_layer<<<3888, 256, 0, stream>>>(
        (const float4*)(qkv_w + (size_t)l * 1728 * D_),
        (const float4*)(out_w + (size_t)l * D_ * D_),
        (const float4*)(fc1_w + (size_t)l * FF_ * D_),
        (const float4*)(fc2_w + (size_t)l * D_ * FF_),
        wq_l, wo_l, w1_l, w2_l);

    // LN1 -> per-chunk {QKV, attn} -> ONE full-M outproj (BM=128: 2232 blocks)
    ln_kernel<<<M_ / 4, 256, 0, stream>>>(h, 576, ln1_w + l * D_, ln1_b + l * D_, ybuf);
    for (int c = 0; c < nch; ++c) {
      long off = (long)c * MC;
      gemm_bt<0, 256><<<dim3(1728 / 64, MC / 256), 256, 0, stream>>>(
          ybuf + off * D_, wq_l, 1728, 576, nullptr, nullptr, cbuf, nullptr, 0);
      attn_kernel<<<(BCc * H_) / 4, 256, 0, stream>>>(cbuf, ybuf + off * D_, scale + l * H_);
    }
    gemm_bt<1, 128><<<dim3(576 / 64, M_ / 128), 256, 0, stream>>>(
        ybuf, wo_l, 576, 576, out_b + l * D_, h, nullptr, nullptr, 0);

    // LN2 -> per-chunk {FC1+gelu (BM=256), FC2+residual (BM=128: 1116 blocks)}
    ln_kernel<<<M_ / 4, 256, 0, stream>>>(h, 576, ln2_w + l * D_, ln2_b + l * D_, ybuf);
    for (int c = 0; c < nch; ++c) {
      long off = (long)c * MC;
      gemm_bt<2, 256><<<dim3(FF_ / 64, MC / 256), 256, 0, stream>>>(
          ybuf + off * D_, w1_l, 2304, 576, fc1_b + l * FF_, nullptr, cbuf, nullptr, 0);
      gemm_bt<1, 128><<<dim3(576 / 64, MC / 128), 256, 0, stream>>>(
          cbuf, w2_l, 576, 2304, fc2_b + l * D_, h + off * D_, nullptr, nullptr, 0);
    }
  }
  // final LN on CLS tokens only (token stride 31*576), then head
  ln_kernel<<<1024 / 4, 256, 0, stream>>>(h, (long)N_ * 576, norm_w, norm_b, cls);
  gemm_bt<3, 128><<<dim3(1024 / 64, 1024 / 128), 256, 0, stream>>>(
      cls, whead, 1024, 576, head_b, nullptr, nullptr, (float*)d_out, NC_);
}